// Round 1
// baseline (20.186 us; speedup 1.0000x reference)
//
#include <hip/hip_runtime.h>
#include <cmath>

#define NPTS 12288
#define DF   128
#define TAUF 0.1f
#define CELL_BITS 18                      // 64^3 cells per batch
#define NCELLS (4 << CELL_BITS)           // 4 batches
#define INVALID_PK 0xFFFFFFFFu

// ---------------- kernel 0: head[] = -1 ----------------
__global__ __launch_bounds__(256) void k_fill(int4* __restrict__ head4)
{
    head4[blockIdx.x * 256 + threadIdx.x] = make_int4(-1, -1, -1, -1);
}

// ---------------- kernel 1: logits + heat + hash-grid insert ----------------
__global__ __launch_bounds__(256) void k_logits(
    const float* __restrict__ feats, const float* __restrict__ W,
    const float* __restrict__ bias, const int* __restrict__ coords,
    float* __restrict__ out_logits, unsigned* __restrict__ pts_pk,
    float* __restrict__ pts_h, int* __restrict__ head, int* __restrict__ nxt)
{
    const int gtid = blockIdx.x * 256 + threadIdx.x;
    const int row  = gtid >> 6;
    const int lane = gtid & 63;
    const float2 f = ((const float2*)(feats + (size_t)row * DF))[lane];
    const float2 w = ((const float2*)W)[lane];
    float s = f.x * w.x + f.y * w.y;
    #pragma unroll
    for (int off = 32; off; off >>= 1) s += __shfl_xor(s, off);
    if (lane == 0) {
        const float logit = s + bias[0];
        out_logits[row] = logit;
        const float heat = 1.0f / (1.0f + expf(-logit));
        const bool valid = heat > TAUF;
        const int4 c = ((const int4*)coords)[row];   // (batch, x, y, z)
        pts_pk[row] = valid ? ((unsigned)c.y | ((unsigned)c.z << 8) |
                               ((unsigned)c.w << 16) | ((unsigned)c.x << 24))
                            : INVALID_PK;
        pts_h[row]  = valid ? heat : -INFINITY;
        if (valid) {
            // exact-coordinate cell: any chain node in a probed neighbor cell
            // satisfies d^2 <= 1.21 by construction (integer grid, radius 1.1)
            const int cell = (c.x << CELL_BITS) | c.y | (c.z << 6) | (c.w << 12);
            nxt[row] = atomicExch(head + cell, row);
        }
    }
}

// ---------------- kernel 2: probe 7 cells -> is_peak -> peaks + feat_mean ----------------
__global__ __launch_bounds__(256) void k_main(
    const float* __restrict__ feats, const int* __restrict__ head,
    const unsigned* __restrict__ pts_pk, const float* __restrict__ pts_h,
    const int* __restrict__ nxt,
    float* __restrict__ out_peaks, float* __restrict__ out_mean)
{
    const int wave = threadIdx.x >> 6;
    const int lane = threadIdx.x & 63;
    const int i    = blockIdx.x * 4 + wave;        // one wave per point

    const unsigned pk = pts_pk[i];
    float2* om = (float2*)(out_mean + (size_t)i * DF);

    if (pk == INVALID_PK) {                        // invalid: zero outputs
        if (lane == 0) ((float4*)out_peaks)[i] = make_float4(0.f, 0.f, 0.f, 0.f);
        om[lane] = make_float2(0.f, 0.f);
        return;
    }

    const int x = pk & 255u, y = (pk >> 8) & 255u, z = (pk >> 16) & 255u, b = pk >> 24;
    const float hi = pts_h[i];

    // lanes 0..6 probe {self, +x, -x, +y, -y, +z, -z}
    int j = -1;
    if (lane < 7) {
        const int nx = x + ((lane == 1) - (lane == 2));
        const int ny = y + ((lane == 3) - (lane == 4));
        const int nz = z + ((lane == 5) - (lane == 6));
        if (((unsigned)nx < 64u) && ((unsigned)ny < 64u) && ((unsigned)nz < 64u))
            j = head[(b << CELL_BITS) | nx | (ny << 6) | (nz << 12)];
    }

    // pass 1: neighborhood max + count (chains expected length ~1)
    float nm = -INFINITY;
    int   cnt = 0;
    for (int t = j; t >= 0; t = nxt[t]) { nm = fmaxf(nm, pts_h[t]); ++cnt; }
    #pragma unroll
    for (int off = 1; off < 8; off <<= 1) {        // reduce lanes 0..7
        nm   = fmaxf(nm, __shfl_xor(nm, off));
        cnt += __shfl_xor(cnt, off);
    }
    nm  = __shfl(nm, 0);                           // broadcast to all 64 lanes
    cnt = __shfl(cnt, 0);

    const bool is_peak = (hi >= nm);               // nm >= hi always (self in chain)
    if (lane == 0) {
        ((float4*)out_peaks)[i] = is_peak
            ? make_float4((float)b, (float)x, (float)y, (float)z)
            : make_float4(0.f, 0.f, 0.f, 0.f);
    }
    if (!is_peak) { om[lane] = make_float2(0.f, 0.f); return; }

    // pass 2: wave-cooperative gather of member feats (cnt iterations total)
    float2 a = make_float2(0.f, 0.f);
    int cur = j;
    for (;;) {
        const unsigned long long bal = __ballot(cur >= 0);
        if (!bal) break;
        const int sl = __builtin_ctzll(bal);
        const int jj = __shfl(cur, sl);
        const float2 fv = ((const float2*)(feats + (size_t)jj * DF))[lane];
        a.x += fv.x; a.y += fv.y;
        if (lane == sl) cur = nxt[cur];
    }
    const float fc = (float)cnt;
    om[lane] = make_float2(a.x / fc, a.y / fc);
}

extern "C" void kernel_launch(void* const* d_in, const int* in_sizes, int n_in,
                              void* d_out, int out_size, void* d_ws, size_t ws_size,
                              hipStream_t stream) {
    const float* feats  = (const float*)d_in[0];
    const float* W      = (const float*)d_in[1];
    const float* bias   = (const float*)d_in[2];
    const int*   coords = (const int*)d_in[3];

    float* out        = (float*)d_out;
    float* out_logits = out;               // N
    float* out_peaks  = out + NPTS;        // N*4
    float* out_mean   = out + NPTS * 5;    // N*128

    int*      head   = (int*)d_ws;                                    // 4 MB
    unsigned* pts_pk = (unsigned*)((char*)d_ws + (4u << 20));         // 48 KB
    float*    pts_h  = (float*)((char*)d_ws + (4u << 20) + 65536);    // 48 KB
    int*      nxt    = (int*)((char*)d_ws + (4u << 20) + 131072);     // 48 KB

    k_fill  <<<NCELLS / 4 / 256, 256, 0, stream>>>((int4*)head);
    k_logits<<<NPTS / 4,         256, 0, stream>>>(feats, W, bias, coords,
                                                   out_logits, pts_pk, pts_h, head, nxt);
    k_main  <<<NPTS / 4,         256, 0, stream>>>(feats, head, pts_pk, pts_h, nxt,
                                                   out_peaks, out_mean);
}